// Round 1
// baseline (458.016 us; speedup 1.0000x reference)
//
#include <hip/hip_runtime.h>
#include <hip/hip_bf16.h>

typedef __bf16 bf16_t;
typedef __bf16 bf16x8 __attribute__((ext_vector_type(8)));
typedef float f32x4 __attribute__((ext_vector_type(4)));

#define F 128
#define KEXP 8
#define BM 64
#define LDH 264
#define LDB 40
#define BTILE (128*LDB)

// ---- degree count (destination = col)
__global__ void k_count(const int* __restrict__ col, int* __restrict__ deg, int E){
  int i = blockIdx.x*256 + threadIdx.x;
  if (i < E) atomicAdd(&deg[col[i]], 1);
}

// ---- exclusive scan over deg -> offs, cursor (single block, 1024 threads)
__global__ void k_scan(const int* __restrict__ deg, int* __restrict__ offs,
                       int* __restrict__ cursor, int Nn){
  __shared__ int lds[1024];
  int t = threadIdx.x;
  int chunk = (Nn + 1023) >> 10;
  int lo = t*chunk, hi = min(lo+chunk, Nn);
  int s = 0;
  for (int i=lo;i<hi;i++) s += deg[i];
  lds[t] = s;
  __syncthreads();
  for (int off=1; off<1024; off<<=1){
    int v = (t>=off) ? lds[t-off] : 0;
    __syncthreads();
    lds[t] += v;
    __syncthreads();
  }
  int run = (t==0) ? 0 : lds[t-1];
  for (int i=lo;i<hi;i++){ offs[i]=run; cursor[i]=run; run += deg[i]; }
  if (t==1023) offs[Nn] = run;
}

// ---- bucket fill: group edge sources by destination
__global__ void k_fill(const int* __restrict__ row, const int* __restrict__ col,
                       int* __restrict__ cursor, int* __restrict__ bucket, int E){
  int i = blockIdx.x*256 + threadIdx.x;
  if (i < E){
    int c = col[i];
    int pos = atomicAdd(&cursor[c], 1);
    bucket[pos] = row[i];
  }
}

// ---- xs[n][f] = bf16( rsqrt(deg[n]) * x[n][f] )   (0 if deg==0)
__global__ void k_prep_xs(const float* __restrict__ x, const int* __restrict__ deg,
                          bf16_t* __restrict__ xs, int total){
  int i = blockIdx.x*256 + threadIdx.x;
  if (i < total){
    int n = i >> 7;
    int d = deg[n];
    float dr = d>0 ? rsqrtf((float)d) : 0.f;
    xs[i] = (bf16_t)(dr * x[i]);
  }
}

// ---- WbT[o][kk] = bf16( W[kk][o] )   (kk = k*256+f, transpose for MFMA B frags)
__global__ void k_prep_w(const float* __restrict__ Wt, bf16_t* __restrict__ WbT){
  int i = blockIdx.x*256 + threadIdx.x; // 2048*128 total
  int o = i >> 11, kk = i & 2047;
  WbT[i] = (bf16_t)Wt[kk*F + o];
}

// ---- gather-aggregate: hi[n] = bf16( rsqrt(deg[n]) * sum_{e->n} xs[row_e] )
__global__ void k_agg(const bf16_t* __restrict__ xs, const int* __restrict__ offs,
                      const int* __restrict__ bucket, bf16_t* __restrict__ hi){
  int n = blockIdx.x, t = threadIdx.x; // 128 threads
  int o0 = offs[n], o1 = offs[n+1];
  float acc = 0.f;
  int j = o0;
  for (; j+4 <= o1; j += 4){
    int r0=bucket[j], r1=bucket[j+1], r2=bucket[j+2], r3=bucket[j+3];
    float a0 = (float)xs[r0*F+t];
    float a1 = (float)xs[r1*F+t];
    float a2 = (float)xs[r2*F+t];
    float a3 = (float)xs[r3*F+t];
    acc += (a0+a1) + (a2+a3);
  }
  for (; j < o1; j++) acc += (float)xs[bucket[j]*F+t];
  int dn = o1 - o0;
  float dc = dn>0 ? rsqrtf((float)dn) : 0.f;
  hi[n*F+t] = (bf16_t)(dc*acc);
}

// ---- fused gated expert GEMM: out = A'(64x2048) @ B'(2048x128) + x
__global__ __launch_bounds__(256) void k_gemm(
    const bf16_t* __restrict__ hi, const float* __restrict__ x,
    const float* __restrict__ e, const bf16_t* __restrict__ WbT,
    float* __restrict__ out, int Nn)
{
  __shared__ alignas(16) bf16_t hc_s[BM*LDH];     // [64][256+8] hicat bf16
  __shared__ alignas(16) bf16_t b_s[2*BTILE];     // double-buffered [128][32+8]
  __shared__ float e_s[BM*KEXP];
  int tid = threadIdx.x;
  int base = blockIdx.x * BM;

  // stage hicat = [hi | bf16(x)]
  for (int u = tid; u < 2048; u += 256){
    int half = u >> 10;
    int v = u & 1023;
    int row = v >> 4, q = v & 15;
    int srow = min(base+row, Nn-1);
    if (half == 0){
      *reinterpret_cast<int4*>(&hc_s[row*LDH + q*8]) =
        *reinterpret_cast<const int4*>(&hi[srow*F + q*8]);
    } else {
      const float4 f0 = *reinterpret_cast<const float4*>(&x[srow*F + q*8]);
      const float4 f1 = *reinterpret_cast<const float4*>(&x[srow*F + q*8 + 4]);
      bf16x8 vv;
      vv[0]=(bf16_t)f0.x; vv[1]=(bf16_t)f0.y; vv[2]=(bf16_t)f0.z; vv[3]=(bf16_t)f0.w;
      vv[4]=(bf16_t)f1.x; vv[5]=(bf16_t)f1.y; vv[6]=(bf16_t)f1.z; vv[7]=(bf16_t)f1.w;
      *reinterpret_cast<bf16x8*>(&hc_s[row*LDH + 128 + q*8]) = vv;
    }
  }
  for (int i = tid; i < BM*KEXP; i += 256){
    int row = i >> 3;
    int srow = min(base+row, Nn-1);
    e_s[i] = e[srow*KEXP + (i&7)];
  }

  int lane = tid & 63, wid = tid >> 6;
  int arow = wid*16 + (lane & 15);
  int kchunk = lane >> 4;

  // B staging: 512 16B units per tile; thread handles units tid, tid+256
  int u0 = tid, u1 = tid + 256;
  int o0u = u0 >> 2, q0u = u0 & 3;
  int o1u = u1 >> 2, q1u = u1 & 3;
  const bf16_t* wsrc0 = WbT + o0u*2048 + q0u*8;
  const bf16_t* wsrc1 = WbT + o1u*2048 + q1u*8;

  int4 breg0 = *reinterpret_cast<const int4*>(wsrc0);
  int4 breg1 = *reinterpret_cast<const int4*>(wsrc1);
  __syncthreads();  // staging of hc_s/e_s done
  *reinterpret_cast<int4*>(&b_s[0*BTILE + o0u*LDB + q0u*8]) = breg0;
  *reinterpret_cast<int4*>(&b_s[0*BTILE + o1u*LDB + q1u*8]) = breg1;
  __syncthreads();

  f32x4 c[8];
  #pragma unroll
  for (int i=0;i<8;i++) c[i] = (f32x4){0.f,0.f,0.f,0.f};

  for (int t=0; t<64; t++){
    if (t < 63){
      breg0 = *reinterpret_cast<const int4*>(wsrc0 + (t+1)*32);
      breg1 = *reinterpret_cast<const int4*>(wsrc1 + (t+1)*32);
    }
    int kk = t >> 3, s = t & 7;
    float evk = e_s[arow*KEXP + kk];
    bf16x8 h = *reinterpret_cast<const bf16x8*>(&hc_s[arow*LDH + s*32 + kchunk*8]);
    bf16x8 a;
    #pragma unroll
    for (int j=0;j<8;j++) a[j] = (bf16_t)(evk * (float)h[j]);
    int boff = (t & 1) * BTILE;
    #pragma unroll
    for (int cg=0; cg<8; cg++){
      bf16x8 b = *reinterpret_cast<const bf16x8*>(&b_s[boff + (cg*16 + (lane&15))*LDB + kchunk*8]);
      c[cg] = __builtin_amdgcn_mfma_f32_16x16x32_bf16(a, b, c[cg], 0, 0, 0);
    }
    if (t < 63){
      int nb = (t+1) & 1;
      *reinterpret_cast<int4*>(&b_s[nb*BTILE + o0u*LDB + q0u*8]) = breg0;
      *reinterpret_cast<int4*>(&b_s[nb*BTILE + o1u*LDB + q1u*8]) = breg1;
    }
    __syncthreads();
  }

  // epilogue: C row = wid*16 + (lane>>4)*4 + r, col = cg*16 + (lane&15)
  int crow0 = (lane >> 4) * 4;
  #pragma unroll
  for (int cg=0; cg<8; cg++){
    int ocol = cg*16 + (lane & 15);
    #pragma unroll
    for (int r=0; r<4; r++){
      int node = base + wid*16 + crow0 + r;
      if (node < Nn){
        out[node*F + ocol] = c[cg][r] + x[node*F + ocol];
      }
    }
  }
}

extern "C" void kernel_launch(void* const* d_in, const int* in_sizes, int n_in,
                              void* d_out, int out_size, void* d_ws, size_t ws_size,
                              hipStream_t stream){
  const float* x  = (const float*)d_in[0];
  const int*  adj = (const int*)d_in[1];
  const float* e  = (const float*)d_in[2];
  const float* W  = (const float*)d_in[3];
  float* out = (float*)d_out;
  int Nn = in_sizes[0] / F;     // 50000
  int E  = in_sizes[1] / 2;     // 1600000
  const int* rowp = adj;
  const int* colp = adj + E;

  char* w = (char*)d_ws;
  auto alloc = [&](size_t b){ char* p = w; w += (b + 255) & ~(size_t)255; return p; };
  int* deg     = (int*)alloc((size_t)Nn*4);
  int* offs    = (int*)alloc(((size_t)Nn+1)*4);
  int* cursor  = (int*)alloc((size_t)Nn*4);
  int* bucket  = (int*)alloc((size_t)E*4);
  bf16_t* xs   = (bf16_t*)alloc((size_t)Nn*F*2);
  bf16_t* hi   = (bf16_t*)alloc((size_t)Nn*F*2);
  bf16_t* WbT  = (bf16_t*)alloc((size_t)2048*F*2);

  hipMemsetAsync(deg, 0, (size_t)Nn*4, stream);
  k_count<<<(E+255)/256, 256, 0, stream>>>(colp, deg, E);
  k_scan<<<1, 1024, 0, stream>>>(deg, offs, cursor, Nn);
  k_fill<<<(E+255)/256, 256, 0, stream>>>(rowp, colp, cursor, bucket, E);
  k_prep_xs<<<(Nn*F+255)/256, 256, 0, stream>>>(x, deg, xs, Nn*F);
  k_prep_w<<<(2048*F+255)/256, 256, 0, stream>>>(W, WbT);
  k_agg<<<Nn, 128, 0, stream>>>(xs, offs, bucket, hi);
  k_gemm<<<(Nn+BM-1)/BM, 256, 0, stream>>>(hi, x, e, WbT, out, Nn);
}

// Round 2
// 212.548 us; speedup vs baseline: 2.1549x; 2.1549x over previous
//
#include <hip/hip_runtime.h>
#include <hip/hip_bf16.h>

typedef __bf16 bf16_t;
typedef __bf16 bf16x8 __attribute__((ext_vector_type(8)));
typedef float f32x4 __attribute__((ext_vector_type(4)));

#define F 128
#define KEXP 8
#define BM 64
#define LDH 264
#define LDB 40
#define BTILE (128*LDB)

#define NB 196          // coarse buckets: col>>8 (256 nodes each)
#define CAP 12288       // per-bucket region capacity (mean 8163, +46 sigma)
#define CH 8192         // edges per binA block

// ---- init per-bucket cursors to region bases
__global__ void k_initcur(int* __restrict__ cursor){
  int t = blockIdx.x*256 + threadIdx.x;
  if (t < NB) cursor[t] = t*CAP;
}

// ---- pass A: coarse-bin edges into per-bucket regions (coalesced-ish runs)
__global__ __launch_bounds__(256) void k_binA(const int* __restrict__ row,
    const int* __restrict__ col, int* __restrict__ cursor,
    int* __restrict__ region, int E){
  __shared__ int stage[CH];               // packed (row<<8)|(col&255)
  __shared__ unsigned char stageb[CH];    // bucket id
  __shared__ int hist[NB];
  __shared__ int lcur[NB];
  int tid = threadIdx.x;
  int base = blockIdx.x * CH;
  int cnt = min(CH, E - base);
  for (int i = tid; i < NB; i += 256) hist[i] = 0;
  __syncthreads();
  for (int i = tid; i < cnt; i += 256){
    int r = row[base+i], c = col[base+i];
    stage[i] = (r << 8) | (c & 255);
    stageb[i] = (unsigned char)(c >> 8);
    atomicAdd(&hist[c >> 8], 1);
  }
  __syncthreads();
  for (int i = tid; i < NB; i += 256)
    lcur[i] = atomicAdd(&cursor[i], hist[i]);
  __syncthreads();
  for (int i = tid; i < cnt; i += 256){
    int b = stageb[i];
    int pos = atomicAdd(&lcur[b], 1);
    region[pos] = stage[i];
  }
}

// ---- scan bucket counts -> global CSR bases; offs[N] = E
__global__ void k_bstart(const int* __restrict__ cursor, int* __restrict__ bstart,
                         int* __restrict__ offs, int Nn){
  __shared__ int lds[256];
  int t = threadIdx.x;
  int c = (t < NB) ? (cursor[t] - t*CAP) : 0;
  lds[t] = c; __syncthreads();
  for (int off=1; off<256; off<<=1){
    int u = (t>=off) ? lds[t-off] : 0;
    __syncthreads();
    lds[t] += u;
    __syncthreads();
  }
  if (t < NB) bstart[t] = lds[t] - c;           // exclusive
  if (t == NB-1){ bstart[NB] = lds[t]; offs[Nn] = lds[t]; }
}

// ---- pass B: per bucket, histogram 256 local dsts -> deg/offs, counting-sort rows
__global__ __launch_bounds__(256) void k_binB(const int* __restrict__ region,
    const int* __restrict__ cursor, const int* __restrict__ bstart,
    int* __restrict__ deg, int* __restrict__ offs, int* __restrict__ bucket,
    int Nn){
  __shared__ int hist[256];
  __shared__ int loff[256];
  __shared__ int lcur[256];
  int b = blockIdx.x, t = threadIdx.x;
  int cnt = cursor[b] - b*CAP;
  const int* src = region + b*CAP;
  hist[t] = 0;
  __syncthreads();
  for (int i = t; i < cnt; i += 256) atomicAdd(&hist[src[i] & 255], 1);
  __syncthreads();
  int v = hist[t];
  loff[t] = v;
  __syncthreads();
  for (int off=1; off<256; off<<=1){
    int u = (t>=off) ? loff[t-off] : 0;
    __syncthreads();
    loff[t] += u;
    __syncthreads();
  }
  int excl = loff[t] - v;
  int gb = bstart[b];
  int node = b*256 + t;
  if (node < Nn){ deg[node] = v; offs[node] = gb + excl; }
  lcur[t] = gb + excl;
  __syncthreads();
  for (int i = t; i < cnt; i += 256){
    int p = src[i];
    int pos = atomicAdd(&lcur[p & 255], 1);
    bucket[pos] = p >> 8;
  }
}

// ---- xs[n][f] = bf16( rsqrt(deg[n]) * x[n][f] )   (0 if deg==0)
__global__ void k_prep_xs(const float* __restrict__ x, const int* __restrict__ deg,
                          bf16_t* __restrict__ xs, int total){
  int i = blockIdx.x*256 + threadIdx.x;
  if (i < total){
    int n = i >> 7;
    int d = deg[n];
    float dr = d>0 ? rsqrtf((float)d) : 0.f;
    xs[i] = (bf16_t)(dr * x[i]);
  }
}

// ---- WbT[o][kk] = bf16( W[kk][o] )
__global__ void k_prep_w(const float* __restrict__ Wt, bf16_t* __restrict__ WbT){
  int i = blockIdx.x*256 + threadIdx.x; // 2048*128 total
  int o = i >> 11, kk = i & 2047;
  WbT[i] = (bf16_t)Wt[kk*F + o];
}

// ---- gather-aggregate: hi[n] = bf16( rsqrt(deg[n]) * sum_{e->n} xs[row_e] )
__global__ void k_agg(const bf16_t* __restrict__ xs, const int* __restrict__ offs,
                      const int* __restrict__ bucket, bf16_t* __restrict__ hi){
  int n = blockIdx.x, t = threadIdx.x; // 128 threads
  int o0 = offs[n], o1 = offs[n+1];
  float acc = 0.f;
  int j = o0;
  for (; j+4 <= o1; j += 4){
    int r0=bucket[j], r1=bucket[j+1], r2=bucket[j+2], r3=bucket[j+3];
    float a0 = (float)xs[r0*F+t];
    float a1 = (float)xs[r1*F+t];
    float a2 = (float)xs[r2*F+t];
    float a3 = (float)xs[r3*F+t];
    acc += (a0+a1) + (a2+a3);
  }
  for (; j < o1; j++) acc += (float)xs[bucket[j]*F+t];
  int dn = o1 - o0;
  float dc = dn>0 ? rsqrtf((float)dn) : 0.f;
  hi[n*F+t] = (bf16_t)(dc*acc);
}

// ---- fused gated expert GEMM: out = A'(64x2048) @ B'(2048x128) + x
__global__ __launch_bounds__(256) void k_gemm(
    const bf16_t* __restrict__ hi, const float* __restrict__ x,
    const float* __restrict__ e, const bf16_t* __restrict__ WbT,
    float* __restrict__ out, int Nn)
{
  __shared__ alignas(16) bf16_t hc_s[BM*LDH];     // [64][256+8] hicat bf16
  __shared__ alignas(16) bf16_t b_s[2*BTILE];     // double-buffered [128][32+8]
  __shared__ float e_s[BM*KEXP];
  int tid = threadIdx.x;
  int base = blockIdx.x * BM;

  for (int u = tid; u < 2048; u += 256){
    int half = u >> 10;
    int v = u & 1023;
    int row = v >> 4, q = v & 15;
    int srow = min(base+row, Nn-1);
    if (half == 0){
      *reinterpret_cast<int4*>(&hc_s[row*LDH + q*8]) =
        *reinterpret_cast<const int4*>(&hi[srow*F + q*8]);
    } else {
      const float4 f0 = *reinterpret_cast<const float4*>(&x[srow*F + q*8]);
      const float4 f1 = *reinterpret_cast<const float4*>(&x[srow*F + q*8 + 4]);
      bf16x8 vv;
      vv[0]=(bf16_t)f0.x; vv[1]=(bf16_t)f0.y; vv[2]=(bf16_t)f0.z; vv[3]=(bf16_t)f0.w;
      vv[4]=(bf16_t)f1.x; vv[5]=(bf16_t)f1.y; vv[6]=(bf16_t)f1.z; vv[7]=(bf16_t)f1.w;
      *reinterpret_cast<bf16x8*>(&hc_s[row*LDH + 128 + q*8]) = vv;
    }
  }
  for (int i = tid; i < BM*KEXP; i += 256){
    int row = i >> 3;
    int srow = min(base+row, Nn-1);
    e_s[i] = e[srow*KEXP + (i&7)];
  }

  int lane = tid & 63, wid = tid >> 6;
  int arow = wid*16 + (lane & 15);
  int kchunk = lane >> 4;

  int u0 = tid, u1 = tid + 256;
  int o0u = u0 >> 2, q0u = u0 & 3;
  int o1u = u1 >> 2, q1u = u1 & 3;
  const bf16_t* wsrc0 = WbT + o0u*2048 + q0u*8;
  const bf16_t* wsrc1 = WbT + o1u*2048 + q1u*8;

  int4 breg0 = *reinterpret_cast<const int4*>(wsrc0);
  int4 breg1 = *reinterpret_cast<const int4*>(wsrc1);
  __syncthreads();
  *reinterpret_cast<int4*>(&b_s[0*BTILE + o0u*LDB + q0u*8]) = breg0;
  *reinterpret_cast<int4*>(&b_s[0*BTILE + o1u*LDB + q1u*8]) = breg1;
  __syncthreads();

  f32x4 c[8];
  #pragma unroll
  for (int i=0;i<8;i++) c[i] = (f32x4){0.f,0.f,0.f,0.f};

  for (int t=0; t<64; t++){
    if (t < 63){
      breg0 = *reinterpret_cast<const int4*>(wsrc0 + (t+1)*32);
      breg1 = *reinterpret_cast<const int4*>(wsrc1 + (t+1)*32);
    }
    int kk = t >> 3, s = t & 7;
    float evk = e_s[arow*KEXP + kk];
    bf16x8 h = *reinterpret_cast<const bf16x8*>(&hc_s[arow*LDH + s*32 + kchunk*8]);
    bf16x8 a;
    #pragma unroll
    for (int j=0;j<8;j++) a[j] = (bf16_t)(evk * (float)h[j]);
    int boff = (t & 1) * BTILE;
    #pragma unroll
    for (int cg=0; cg<8; cg++){
      bf16x8 b = *reinterpret_cast<const bf16x8*>(&b_s[boff + (cg*16 + (lane&15))*LDB + kchunk*8]);
      c[cg] = __builtin_amdgcn_mfma_f32_16x16x32_bf16(a, b, c[cg], 0, 0, 0);
    }
    if (t < 63){
      int nb = (t+1) & 1;
      *reinterpret_cast<int4*>(&b_s[nb*BTILE + o0u*LDB + q0u*8]) = breg0;
      *reinterpret_cast<int4*>(&b_s[nb*BTILE + o1u*LDB + q1u*8]) = breg1;
    }
    __syncthreads();
  }

  int crow0 = (lane >> 4) * 4;
  #pragma unroll
  for (int cg=0; cg<8; cg++){
    int ocol = cg*16 + (lane & 15);
    #pragma unroll
    for (int r=0; r<4; r++){
      int node = base + wid*16 + crow0 + r;
      if (node < Nn){
        out[node*F + ocol] = c[cg][r] + x[node*F + ocol];
      }
    }
  }
}

extern "C" void kernel_launch(void* const* d_in, const int* in_sizes, int n_in,
                              void* d_out, int out_size, void* d_ws, size_t ws_size,
                              hipStream_t stream){
  const float* x  = (const float*)d_in[0];
  const int*  adj = (const int*)d_in[1];
  const float* e  = (const float*)d_in[2];
  const float* W  = (const float*)d_in[3];
  float* out = (float*)d_out;
  int Nn = in_sizes[0] / F;     // 50000
  int E  = in_sizes[1] / 2;     // 1600000
  const int* rowp = adj;
  const int* colp = adj + E;

  char* w = (char*)d_ws;
  auto alloc = [&](size_t b){ char* p = w; w += (b + 255) & ~(size_t)255; return p; };
  int* deg     = (int*)alloc((size_t)Nn*4);
  int* offs    = (int*)alloc(((size_t)Nn+1)*4);
  int* cursor  = (int*)alloc((size_t)NB*4);
  int* bstart  = (int*)alloc((size_t)(NB+1)*4);
  int* bucket  = (int*)alloc((size_t)E*4);
  // region (NB*CAP*4 = 9.63MB) aliased over xs (12.8MB): region is dead after
  // k_binB, xs written only from k_prep_xs onward (stream-ordered).
  char* uni    = alloc((size_t)Nn*F*2 > (size_t)NB*CAP*4 ? (size_t)Nn*F*2
                                                          : (size_t)NB*CAP*4);
  int* region  = (int*)uni;
  bf16_t* xs   = (bf16_t*)uni;
  bf16_t* hi   = (bf16_t*)alloc((size_t)Nn*F*2);
  bf16_t* WbT  = (bf16_t*)alloc((size_t)2048*F*2);

  int nchunks = (E + CH - 1) / CH;
  k_initcur<<<1, 256, 0, stream>>>(cursor);
  k_binA<<<nchunks, 256, 0, stream>>>(rowp, colp, cursor, region, E);
  k_bstart<<<1, 256, 0, stream>>>(cursor, bstart, offs, Nn);
  k_binB<<<NB, 256, 0, stream>>>(region, cursor, bstart, deg, offs, bucket, Nn);
  k_prep_xs<<<(Nn*F+255)/256, 256, 0, stream>>>(x, deg, xs, Nn*F);
  k_prep_w<<<(2048*F+255)/256, 256, 0, stream>>>(W, WbT);
  k_agg<<<Nn, 128, 0, stream>>>(xs, offs, bucket, hi);
  k_gemm<<<(Nn+BM-1)/BM, 256, 0, stream>>>(hi, x, e, WbT, out, Nn);
}

// Round 3
// 189.570 us; speedup vs baseline: 2.4161x; 1.1212x over previous
//
#include <hip/hip_runtime.h>
#include <hip/hip_bf16.h>

typedef __bf16 bf16_t;
typedef __bf16 bf16x8 __attribute__((ext_vector_type(8)));
typedef float f32x4 __attribute__((ext_vector_type(4)));

#define F 128
#define KEXP 8
#define BM 64
#define LDH 264
#define BTILE (128*32)

#define NB 196          // coarse buckets: col>>8 (256 nodes each)
#define CAP 12288       // per-bucket region capacity
#define CH 8192         // edges per binA block

// ---- init per-bucket cursors to region bases
__global__ void k_initcur(int* __restrict__ cursor){
  int t = blockIdx.x*256 + threadIdx.x;
  if (t < NB) cursor[t] = t*CAP;
}

// ---- pass A: coarse-bin edges into per-bucket regions
__global__ __launch_bounds__(256) void k_binA(const int* __restrict__ row,
    const int* __restrict__ col, int* __restrict__ cursor,
    int* __restrict__ region, int E){
  __shared__ int stage[CH];
  __shared__ unsigned char stageb[CH];
  __shared__ int hist[NB];
  __shared__ int lcur[NB];
  int tid = threadIdx.x;
  int base = blockIdx.x * CH;
  int cnt = min(CH, E - base);
  for (int i = tid; i < NB; i += 256) hist[i] = 0;
  __syncthreads();
  for (int i = tid; i < cnt; i += 256){
    int r = row[base+i], c = col[base+i];
    stage[i] = (r << 8) | (c & 255);
    stageb[i] = (unsigned char)(c >> 8);
    atomicAdd(&hist[c >> 8], 1);
  }
  __syncthreads();
  for (int i = tid; i < NB; i += 256)
    lcur[i] = atomicAdd(&cursor[i], hist[i]);
  __syncthreads();
  for (int i = tid; i < cnt; i += 256){
    int b = stageb[i];
    int pos = atomicAdd(&lcur[b], 1);
    region[pos] = stage[i];
  }
}

// ---- scan bucket counts -> global CSR bases; offs[N] = E
__global__ void k_bstart(const int* __restrict__ cursor, int* __restrict__ bstart,
                         int* __restrict__ offs, int Nn){
  __shared__ int lds[256];
  int t = threadIdx.x;
  int c = (t < NB) ? (cursor[t] - t*CAP) : 0;
  lds[t] = c; __syncthreads();
  for (int off=1; off<256; off<<=1){
    int u = (t>=off) ? lds[t-off] : 0;
    __syncthreads();
    lds[t] += u;
    __syncthreads();
  }
  if (t < NB) bstart[t] = lds[t] - c;
  if (t == NB-1){ bstart[NB] = lds[t]; offs[Nn] = lds[t]; }
}

// ---- pass B: per bucket, histogram 256 local dsts -> deg/offs, counting-sort
__global__ __launch_bounds__(256) void k_binB(const int* __restrict__ region,
    const int* __restrict__ cursor, const int* __restrict__ bstart,
    int* __restrict__ deg, int* __restrict__ offs, int* __restrict__ bucket,
    int Nn){
  __shared__ int hist[256];
  __shared__ int loff[256];
  __shared__ int lcur[256];
  int b = blockIdx.x, t = threadIdx.x;
  int cnt = cursor[b] - b*CAP;
  const int* src = region + b*CAP;
  hist[t] = 0;
  __syncthreads();
  for (int i = t; i < cnt; i += 256) atomicAdd(&hist[src[i] & 255], 1);
  __syncthreads();
  int v = hist[t];
  loff[t] = v;
  __syncthreads();
  for (int off=1; off<256; off<<=1){
    int u = (t>=off) ? loff[t-off] : 0;
    __syncthreads();
    loff[t] += u;
    __syncthreads();
  }
  int excl = loff[t] - v;
  int gb = bstart[b];
  int node = b*256 + t;
  if (node < Nn){ deg[node] = v; offs[node] = gb + excl; }
  lcur[t] = gb + excl;
  __syncthreads();
  for (int i = t; i < cnt; i += 256){
    int p = src[i];
    int pos = atomicAdd(&lcur[p & 255], 1);
    bucket[pos] = p >> 8;
  }
}

// ---- xs[n][f] = bf16( rsqrt(deg[n]) * x[n][f] )  — vectorized x8
__global__ void k_prep_xs(const float* __restrict__ x, const int* __restrict__ deg,
                          bf16_t* __restrict__ xs, int total8){
  int i = blockIdx.x*256 + threadIdx.x;   // one per 8 elems
  if (i < total8){
    int n = i >> 4;                       // 16 groups of 8 per row
    int d = deg[n];
    float dr = d>0 ? rsqrtf((float)d) : 0.f;
    const float4 f0 = *reinterpret_cast<const float4*>(&x[i*8]);
    const float4 f1 = *reinterpret_cast<const float4*>(&x[i*8+4]);
    bf16x8 v;
    v[0]=(bf16_t)(dr*f0.x); v[1]=(bf16_t)(dr*f0.y);
    v[2]=(bf16_t)(dr*f0.z); v[3]=(bf16_t)(dr*f0.w);
    v[4]=(bf16_t)(dr*f1.x); v[5]=(bf16_t)(dr*f1.y);
    v[6]=(bf16_t)(dr*f1.z); v[7]=(bf16_t)(dr*f1.w);
    *reinterpret_cast<bf16x8*>(&xs[i*8]) = v;
  }
}

// ---- WbT[o][kk] = bf16( W[kk][o] )
__global__ void k_prep_w(const float* __restrict__ Wt, bf16_t* __restrict__ WbT){
  int i = blockIdx.x*256 + threadIdx.x; // 2048*128 total
  int o = i >> 11, kk = i & 2047;
  WbT[i] = (bf16_t)Wt[kk*F + o];
}

// ---- gather-aggregate, wave-per-node: 16 lanes x bf16x8 cover one 256B row
__global__ __launch_bounds__(256) void k_agg(const bf16_t* __restrict__ xs,
    const int* __restrict__ offs, const int* __restrict__ bucket,
    bf16_t* __restrict__ hi, int Nn){
  int wid = threadIdx.x >> 6, lane = threadIdx.x & 63;
  int n = blockIdx.x*4 + wid;
  if (n >= Nn) return;
  int g = lane >> 4, j16 = lane & 15;
  int o0 = offs[n], o1 = offs[n+1];
  float acc[8] = {0.f,0.f,0.f,0.f,0.f,0.f,0.f,0.f};
  int j = o0 + g;
  for (; j + 4 < o1; j += 8){
    int r0 = bucket[j];
    int r1 = bucket[j+4];
    bf16x8 v0 = *reinterpret_cast<const bf16x8*>(&xs[(size_t)r0*F + j16*8]);
    bf16x8 v1 = *reinterpret_cast<const bf16x8*>(&xs[(size_t)r1*F + j16*8]);
    #pragma unroll
    for (int i=0;i<8;i++) acc[i] += (float)v0[i] + (float)v1[i];
  }
  if (j < o1){
    int r0 = bucket[j];
    bf16x8 v0 = *reinterpret_cast<const bf16x8*>(&xs[(size_t)r0*F + j16*8]);
    #pragma unroll
    for (int i=0;i<8;i++) acc[i] += (float)v0[i];
  }
  #pragma unroll
  for (int i=0;i<8;i++){
    acc[i] += __shfl_down(acc[i], 32);
    acc[i] += __shfl_down(acc[i], 16);
  }
  if (g == 0){
    int dn = o1 - o0;
    float dc = dn>0 ? rsqrtf((float)dn) : 0.f;
    bf16x8 o;
    #pragma unroll
    for (int i=0;i<8;i++) o[i] = (bf16_t)(dc*acc[i]);
    *reinterpret_cast<bf16x8*>(&hi[(size_t)n*F + j16*8]) = o;
  }
}

// ---- fused gated expert GEMM: out = sum_k e[:,k] * (hicat @ W[k]) + x
// A-frags hoisted to regs; gating on C side; b_s swizzled conflict-free;
// b_s aliases hc_s region after A-frag hoist (35KB LDS total).
__global__ __launch_bounds__(256) void k_gemm(
    const bf16_t* __restrict__ hi, const float* __restrict__ x,
    const float* __restrict__ e, const bf16_t* __restrict__ WbT,
    float* __restrict__ out, int Nn)
{
  __shared__ char smem[BM*LDH*2 + BM*KEXP*4];   // 33792 + 2048
  bf16_t* hc_s = (bf16_t*)smem;                 // [64][264]
  float*  e_s  = (float*)(smem + BM*LDH*2);     // [64][8]
  bf16_t* b_s  = (bf16_t*)smem;                 // 2x[128][32] swizzled (aliases hc_s)

  int tid = threadIdx.x;
  int base = blockIdx.x * BM;

  // stage hicat = [hi | bf16(x)]
  for (int u = tid; u < 2048; u += 256){
    int half = u >> 10;
    int v = u & 1023;
    int row = v >> 4, q = v & 15;
    int srow = min(base+row, Nn-1);
    if (half == 0){
      *reinterpret_cast<int4*>(&hc_s[row*LDH + q*8]) =
        *reinterpret_cast<const int4*>(&hi[srow*F + q*8]);
    } else {
      const float4 f0 = *reinterpret_cast<const float4*>(&x[srow*F + q*8]);
      const float4 f1 = *reinterpret_cast<const float4*>(&x[srow*F + q*8 + 4]);
      bf16x8 vv;
      vv[0]=(bf16_t)f0.x; vv[1]=(bf16_t)f0.y; vv[2]=(bf16_t)f0.z; vv[3]=(bf16_t)f0.w;
      vv[4]=(bf16_t)f1.x; vv[5]=(bf16_t)f1.y; vv[6]=(bf16_t)f1.z; vv[7]=(bf16_t)f1.w;
      *reinterpret_cast<bf16x8*>(&hc_s[row*LDH + 128 + q*8]) = vv;
    }
  }
  for (int i = tid; i < BM*KEXP; i += 256){
    int row = i >> 3;
    int srow = min(base+row, Nn-1);
    e_s[i] = e[srow*KEXP + (i&7)];
  }

  int lane = tid & 63, wid = tid >> 6;
  int arow = wid*16 + (lane & 15);
  int kchunk = lane >> 4;

  // B staging addresses: unit u -> row o (0..127), chunk q (0..3)
  int o0u = tid >> 1, q0u = (tid & 1);           // units 2*tid, 2*tid+1 -> q = 0,1 / 2,3
  // simpler: unit0 = tid (o=tid>>2,q=tid&3), unit1 = tid+256
  int oA = tid >> 2,        qA = tid & 3;
  int oB = (tid+256) >> 2,  qB = tid & 3;        // (tid+256)&3 == tid&3
  const bf16_t* wsrcA = WbT + oA*2048 + qA*8;
  const bf16_t* wsrcB = WbT + oB*2048 + qB*8;
  int sA = oA*32 + ((qA + (oA>>2)) & 3)*8;       // swizzled LDS elem offset
  int sB = oB*32 + ((qB + (oB>>2)) & 3)*8;
  (void)o0u; (void)q0u;

  int4 bregA = *reinterpret_cast<const int4*>(wsrcA);
  int4 bregB = *reinterpret_cast<const int4*>(wsrcB);

  __syncthreads();   // hc_s/e_s staged

  // hoist A-frags (pure hicat, shared across all 8 experts)
  bf16x8 a[8];
  #pragma unroll
  for (int s=0;s<8;s++)
    a[s] = *reinterpret_cast<const bf16x8*>(&hc_s[arow*LDH + s*32 + kchunk*8]);

  __syncthreads();   // a-frag reads done; safe to clobber hc_s with b_s

  *reinterpret_cast<int4*>(&b_s[0*BTILE + sA]) = bregA;
  *reinterpret_cast<int4*>(&b_s[0*BTILE + sB]) = bregB;
  __syncthreads();

  f32x4 acc[8];
  #pragma unroll
  for (int i=0;i<8;i++) acc[i] = (f32x4){0.f,0.f,0.f,0.f};

  int r4 = (lane >> 4) * 4;           // row base within wave tile for C
  // precomputed swizzled read offsets for the 8 col-groups
  for (int kk=0; kk<8; kk++){
    f32x4 ck[8];
    #pragma unroll
    for (int i=0;i<8;i++) ck[i] = (f32x4){0.f,0.f,0.f,0.f};
    #pragma unroll
    for (int s=0;s<8;s++){
      int t = kk*8 + s;
      if (t < 63){
        bregA = *reinterpret_cast<const int4*>(wsrcA + (t+1)*32);
        bregB = *reinterpret_cast<const int4*>(wsrcB + (t+1)*32);
      }
      int boff = (t & 1) * BTILE;
      #pragma unroll
      for (int cg=0; cg<8; cg++){
        int brow = cg*16 + (lane & 15);
        int slot = (kchunk + (brow >> 2)) & 3;
        bf16x8 b = *reinterpret_cast<const bf16x8*>(&b_s[boff + brow*32 + slot*8]);
        ck[cg] = __builtin_amdgcn_mfma_f32_16x16x32_bf16(a[s], b, ck[cg], 0, 0, 0);
      }
      if (t < 63){
        int nb = (t+1) & 1;
        *reinterpret_cast<int4*>(&b_s[nb*BTILE + sA]) = bregA;
        *reinterpret_cast<int4*>(&b_s[nb*BTILE + sB]) = bregB;
      }
      __syncthreads();
    }
    float e0 = e_s[(wid*16 + r4 + 0)*KEXP + kk];
    float e1 = e_s[(wid*16 + r4 + 1)*KEXP + kk];
    float e2 = e_s[(wid*16 + r4 + 2)*KEXP + kk];
    float e3 = e_s[(wid*16 + r4 + 3)*KEXP + kk];
    #pragma unroll
    for (int cg=0; cg<8; cg++){
      acc[cg][0] += e0*ck[cg][0];
      acc[cg][1] += e1*ck[cg][1];
      acc[cg][2] += e2*ck[cg][2];
      acc[cg][3] += e3*ck[cg][3];
    }
  }

  #pragma unroll
  for (int cg=0; cg<8; cg++){
    int ocol = cg*16 + (lane & 15);
    #pragma unroll
    for (int r=0; r<4; r++){
      int node = base + wid*16 + r4 + r;
      if (node < Nn){
        out[node*F + ocol] = acc[cg][r] + x[node*F + ocol];
      }
    }
  }
}

extern "C" void kernel_launch(void* const* d_in, const int* in_sizes, int n_in,
                              void* d_out, int out_size, void* d_ws, size_t ws_size,
                              hipStream_t stream){
  const float* x  = (const float*)d_in[0];
  const int*  adj = (const int*)d_in[1];
  const float* e  = (const float*)d_in[2];
  const float* W  = (const float*)d_in[3];
  float* out = (float*)d_out;
  int Nn = in_sizes[0] / F;     // 50000
  int E  = in_sizes[1] / 2;     // 1600000
  const int* rowp = adj;
  const int* colp = adj + E;

  char* w = (char*)d_ws;
  auto alloc = [&](size_t b){ char* p = w; w += (b + 255) & ~(size_t)255; return p; };
  int* deg     = (int*)alloc((size_t)Nn*4);
  int* offs    = (int*)alloc(((size_t)Nn+1)*4);
  int* cursor  = (int*)alloc((size_t)NB*4);
  int* bstart  = (int*)alloc((size_t)(NB+1)*4);
  int* bucket  = (int*)alloc((size_t)E*4);
  char* uni    = alloc((size_t)Nn*F*2 > (size_t)NB*CAP*4 ? (size_t)Nn*F*2
                                                          : (size_t)NB*CAP*4);
  int* region  = (int*)uni;      // dead after k_binB
  bf16_t* xs   = (bf16_t*)uni;   // live from k_prep_xs
  bf16_t* hi   = (bf16_t*)alloc((size_t)Nn*F*2);
  bf16_t* WbT  = (bf16_t*)alloc((size_t)2048*F*2);

  int nchunks = (E + CH - 1) / CH;
  k_initcur<<<1, 256, 0, stream>>>(cursor);
  k_binA<<<nchunks, 256, 0, stream>>>(rowp, colp, cursor, region, E);
  k_bstart<<<1, 256, 0, stream>>>(cursor, bstart, offs, Nn);
  k_binB<<<NB, 256, 0, stream>>>(region, cursor, bstart, deg, offs, bucket, Nn);
  k_prep_xs<<<(Nn*F/8+255)/256, 256, 0, stream>>>(x, deg, xs, Nn*F/8);
  k_prep_w<<<(2048*F+255)/256, 256, 0, stream>>>(W, WbT);
  k_agg<<<(Nn+3)/4, 256, 0, stream>>>(xs, offs, bucket, hi, Nn);
  k_gemm<<<(Nn+BM-1)/BM, 256, 0, stream>>>(hi, x, e, WbT, out, Nn);
}

// Round 4
// 187.473 us; speedup vs baseline: 2.4431x; 1.0112x over previous
//
#include <hip/hip_runtime.h>
#include <hip/hip_bf16.h>

typedef __bf16 bf16_t;
typedef __bf16 bf16x8 __attribute__((ext_vector_type(8)));
typedef float f32x4 __attribute__((ext_vector_type(4)));

#define F 128
#define KEXP 8
#define BM 128
#define LDH 264
#define NSTAGE 32
#define STG_ELEMS 8192   // 128 rows x 64 k per stage

#define NB 196          // coarse buckets: col>>8 (256 nodes each)
#define CAP 12288       // per-bucket region capacity
#define CH 8192         // edges per binA block

// ---- init per-bucket cursors to region bases
__global__ void k_initcur(int* __restrict__ cursor){
  int t = blockIdx.x*256 + threadIdx.x;
  if (t < NB) cursor[t] = t*CAP;
}

// ---- pass A: coarse-bin edges into per-bucket regions
__global__ __launch_bounds__(256) void k_binA(const int* __restrict__ row,
    const int* __restrict__ col, int* __restrict__ cursor,
    int* __restrict__ region, int E){
  __shared__ int stage[CH];
  __shared__ unsigned char stageb[CH];
  __shared__ int hist[NB];
  __shared__ int lcur[NB];
  int tid = threadIdx.x;
  int base = blockIdx.x * CH;
  int cnt = min(CH, E - base);
  for (int i = tid; i < NB; i += 256) hist[i] = 0;
  __syncthreads();
  for (int i = tid; i < cnt; i += 256){
    int r = row[base+i], c = col[base+i];
    stage[i] = (r << 8) | (c & 255);
    stageb[i] = (unsigned char)(c >> 8);
    atomicAdd(&hist[c >> 8], 1);
  }
  __syncthreads();
  for (int i = tid; i < NB; i += 256)
    lcur[i] = atomicAdd(&cursor[i], hist[i]);
  __syncthreads();
  for (int i = tid; i < cnt; i += 256){
    int b = stageb[i];
    int pos = atomicAdd(&lcur[b], 1);
    region[pos] = stage[i];
  }
}

// ---- scan bucket counts -> global CSR bases; offs[N] = E
__global__ void k_bstart(const int* __restrict__ cursor, int* __restrict__ bstart,
                         int* __restrict__ offs, int Nn){
  __shared__ int lds[256];
  int t = threadIdx.x;
  int c = (t < NB) ? (cursor[t] - t*CAP) : 0;
  lds[t] = c; __syncthreads();
  for (int off=1; off<256; off<<=1){
    int u = (t>=off) ? lds[t-off] : 0;
    __syncthreads();
    lds[t] += u;
    __syncthreads();
  }
  if (t < NB) bstart[t] = lds[t] - c;
  if (t == NB-1){ bstart[NB] = lds[t]; offs[Nn] = lds[t]; }
}

// ---- pass B: per bucket, histogram 256 local dsts -> deg/offs, counting-sort
__global__ __launch_bounds__(256) void k_binB(const int* __restrict__ region,
    const int* __restrict__ cursor, const int* __restrict__ bstart,
    int* __restrict__ deg, int* __restrict__ offs, int* __restrict__ bucket,
    int Nn){
  __shared__ int hist[256];
  __shared__ int loff[256];
  __shared__ int lcur[256];
  int b = blockIdx.x, t = threadIdx.x;
  int cnt = cursor[b] - b*CAP;
  const int* src = region + b*CAP;
  hist[t] = 0;
  __syncthreads();
  for (int i = t; i < cnt; i += 256) atomicAdd(&hist[src[i] & 255], 1);
  __syncthreads();
  int v = hist[t];
  loff[t] = v;
  __syncthreads();
  for (int off=1; off<256; off<<=1){
    int u = (t>=off) ? loff[t-off] : 0;
    __syncthreads();
    loff[t] += u;
    __syncthreads();
  }
  int excl = loff[t] - v;
  int gb = bstart[b];
  int node = b*256 + t;
  if (node < Nn){ deg[node] = v; offs[node] = gb + excl; }
  lcur[t] = gb + excl;
  __syncthreads();
  for (int i = t; i < cnt; i += 256){
    int p = src[i];
    int pos = atomicAdd(&lcur[p & 255], 1);
    bucket[pos] = p >> 8;
  }
}

// ---- xs[n][f] = bf16( rsqrt(deg[n]) * x[n][f] )  — vectorized x8
__global__ void k_prep_xs(const float* __restrict__ x, const int* __restrict__ deg,
                          bf16_t* __restrict__ xs, int total8){
  int i = blockIdx.x*256 + threadIdx.x;
  if (i < total8){
    int n = i >> 4;
    int d = deg[n];
    float dr = d>0 ? rsqrtf((float)d) : 0.f;
    const float4 f0 = *reinterpret_cast<const float4*>(&x[i*8]);
    const float4 f1 = *reinterpret_cast<const float4*>(&x[i*8+4]);
    bf16x8 v;
    v[0]=(bf16_t)(dr*f0.x); v[1]=(bf16_t)(dr*f0.y);
    v[2]=(bf16_t)(dr*f0.z); v[3]=(bf16_t)(dr*f0.w);
    v[4]=(bf16_t)(dr*f1.x); v[5]=(bf16_t)(dr*f1.y);
    v[6]=(bf16_t)(dr*f1.z); v[7]=(bf16_t)(dr*f1.w);
    *reinterpret_cast<bf16x8*>(&xs[i*8]) = v;
  }
}

// ---- Wt: pre-tiled + pre-swizzled B for k_gemm.
// Wt[st*8192 + o*64 + (slot^(o&7))*8 + j] = bf16( W[k>>8][k&255][o] ),
// k = st*64 + slot*8 + j.  k_gemm staging is then a contiguous copy and
// swizzled ds_reads are conflict-free (<=2-way).
__global__ void k_prep_w(const float* __restrict__ W, bf16_t* __restrict__ Wt){
  int i8 = blockIdx.x*256 + threadIdx.x;   // 32768 total, 8 elems each
  if (i8 >= 32768) return;
  int st = i8 >> 10;
  int w  = i8 & 1023;
  int o  = w >> 3;
  int sp = w & 7;                 // slot'
  int slot = sp ^ (o & 7);
  bf16x8 v;
  #pragma unroll
  for (int j=0;j<8;j++){
    int k = st*64 + slot*8 + j;
    v[j] = (bf16_t)W[(size_t)(k>>8)*32768 + (size_t)(k&255)*128 + o];
  }
  *reinterpret_cast<bf16x8*>(&Wt[(size_t)i8*8]) = v;
}

// ---- gather-aggregate, wave-per-node: 16 lanes x bf16x8 cover one 256B row
__global__ __launch_bounds__(256) void k_agg(const bf16_t* __restrict__ xs,
    const int* __restrict__ offs, const int* __restrict__ bucket,
    bf16_t* __restrict__ hi, int Nn){
  int wid = threadIdx.x >> 6, lane = threadIdx.x & 63;
  int n = blockIdx.x*4 + wid;
  if (n >= Nn) return;
  int g = lane >> 4, j16 = lane & 15;
  int o0 = offs[n], o1 = offs[n+1];
  float acc[8] = {0.f,0.f,0.f,0.f,0.f,0.f,0.f,0.f};
  int j = o0 + g;
  for (; j + 12 < o1; j += 16){
    int r0 = bucket[j];
    int r1 = bucket[j+4];
    int r2 = bucket[j+8];
    int r3 = bucket[j+12];
    bf16x8 v0 = *reinterpret_cast<const bf16x8*>(&xs[(size_t)r0*F + j16*8]);
    bf16x8 v1 = *reinterpret_cast<const bf16x8*>(&xs[(size_t)r1*F + j16*8]);
    bf16x8 v2 = *reinterpret_cast<const bf16x8*>(&xs[(size_t)r2*F + j16*8]);
    bf16x8 v3 = *reinterpret_cast<const bf16x8*>(&xs[(size_t)r3*F + j16*8]);
    #pragma unroll
    for (int i=0;i<8;i++)
      acc[i] += ((float)v0[i] + (float)v1[i]) + ((float)v2[i] + (float)v3[i]);
  }
  for (; j < o1; j += 4){
    int r0 = bucket[j];
    bf16x8 v0 = *reinterpret_cast<const bf16x8*>(&xs[(size_t)r0*F + j16*8]);
    #pragma unroll
    for (int i=0;i<8;i++) acc[i] += (float)v0[i];
  }
  #pragma unroll
  for (int i=0;i<8;i++){
    acc[i] += __shfl_down(acc[i], 32);
    acc[i] += __shfl_down(acc[i], 16);
  }
  if (g == 0){
    int dn = o1 - o0;
    float dc = dn>0 ? rsqrtf((float)dn) : 0.f;
    bf16x8 o;
    #pragma unroll
    for (int i=0;i<8;i++) o[i] = (bf16_t)(dc*acc[i]);
    *reinterpret_cast<bf16x8*>(&hi[(size_t)n*F + j16*8]) = o;
  }
}

// ---- fused gated expert GEMM: out = sum_k e[:,k]*(hicat @ W[k]) + x
// 4 waves x 32 rows; A-frags for full K=256 hicat held in regs (reused across
// all 8 experts); B streamed via 32 pre-swizzled 16KB stages, single barrier
// per stage, issue-early/write-late double buffer; per-expert ck folded into
// acc with e gates.
__global__ __launch_bounds__(256, 2) void k_gemm(
    const bf16_t* __restrict__ hi, const float* __restrict__ x,
    const float* __restrict__ e, const bf16_t* __restrict__ Wt,
    float* __restrict__ out, int Nn)
{
  __shared__ alignas(16) char smem[BM*LDH*2 + BM*KEXP*4];  // 67584 + 4096
  bf16_t* hc_s = (bf16_t*)smem;                 // [128][264] staging (transient)
  bf16_t* b_s  = (bf16_t*)smem;                 // 2 x 16KB stage buffers (alias)
  float*  e_s  = (float*)(smem + BM*LDH*2);     // [128][8]

  int tid = threadIdx.x;
  int base = blockIdx.x * BM;
  int lane = tid & 63, wid = tid >> 6;
  int r16 = lane & 15, kchunk = lane >> 4;

  // ---- stage hicat = [hi | bf16(x)] for rows [base, base+128)
  for (int u = tid; u < 2048; u += 256){
    int row = u >> 4, q = u & 15;
    int srow = min(base + row, Nn-1);
    *reinterpret_cast<int4*>(&hc_s[row*LDH + q*8]) =
      *reinterpret_cast<const int4*>(&hi[(size_t)srow*F + q*8]);
  }
  for (int u = tid; u < 2048; u += 256){
    int row = u >> 4, q = u & 15;
    int srow = min(base + row, Nn-1);
    const float4 f0 = *reinterpret_cast<const float4*>(&x[(size_t)srow*F + q*8]);
    const float4 f1 = *reinterpret_cast<const float4*>(&x[(size_t)srow*F + q*8 + 4]);
    bf16x8 vv;
    vv[0]=(bf16_t)f0.x; vv[1]=(bf16_t)f0.y; vv[2]=(bf16_t)f0.z; vv[3]=(bf16_t)f0.w;
    vv[4]=(bf16_t)f1.x; vv[5]=(bf16_t)f1.y; vv[6]=(bf16_t)f1.z; vv[7]=(bf16_t)f1.w;
    *reinterpret_cast<bf16x8*>(&hc_s[row*LDH + 128 + q*8]) = vv;
  }
  {
    int row = tid >> 1;
    int srow = min(base + row, Nn-1);
    float4 ev = *reinterpret_cast<const float4*>(&e[(size_t)srow*KEXP + (tid&1)*4]);
    *reinterpret_cast<float4*>(&e_s[tid*4]) = ev;
  }
  __syncthreads();

  // ---- hoist A-frags: rows wid*32+r16 (+16), full hicat K=256
  int row0 = wid*32 + r16;
  bf16x8 a[2][8];
  #pragma unroll
  for (int s=0;s<8;s++){
    a[0][s] = *reinterpret_cast<const bf16x8*>(&hc_s[row0*LDH + s*32 + kchunk*8]);
    a[1][s] = *reinterpret_cast<const bf16x8*>(&hc_s[(row0+16)*LDH + s*32 + kchunk*8]);
  }
  __syncthreads();   // hc_s dead; b_s takes over

  // ---- B pipeline prologue: stage 0
  int4 breg[4];
  #pragma unroll
  for (int i=0;i<4;i++)
    breg[i] = *reinterpret_cast<const int4*>(&Wt[(size_t)(i*256+tid)*8]);
  #pragma unroll
  for (int i=0;i<4;i++)
    *reinterpret_cast<int4*>(&b_s[(i*256+tid)*8]) = breg[i];
  __syncthreads();

  f32x4 acc[2][8], ck[2][8];
  #pragma unroll
  for (int rg=0;rg<2;rg++)
    #pragma unroll
    for (int cg=0;cg<8;cg++){
      acc[rg][cg] = (f32x4){0.f,0.f,0.f,0.f};
      ck[rg][cg]  = (f32x4){0.f,0.f,0.f,0.f};
    }

  for (int st=0; st<NSTAGE; st++){
    if (st+1 < NSTAGE){
      #pragma unroll
      for (int i=0;i<4;i++)
        breg[i] = *reinterpret_cast<const int4*>(
            &Wt[(size_t)(st+1)*STG_ELEMS + (size_t)(i*256+tid)*8]);
    }
    const bf16_t* buf = b_s + (st&1)*STG_ELEMS;
    int se = st & 3;
    #pragma unroll
    for (int t=0; t<2; t++){
      int slot = t*4 + kchunk;
      int sa = se*2 + t;
      #pragma unroll
      for (int cg=0; cg<8; cg++){
        int brow = cg*16 + r16;
        bf16x8 b = *reinterpret_cast<const bf16x8*>(
            &buf[brow*64 + ((slot ^ (brow&7))*8)]);
        ck[0][cg] = __builtin_amdgcn_mfma_f32_16x16x32_bf16(a[0][sa], b, ck[0][cg], 0, 0, 0);
        ck[1][cg] = __builtin_amdgcn_mfma_f32_16x16x32_bf16(a[1][sa], b, ck[1][cg], 0, 0, 0);
      }
    }
    if ((st & 3) == 3){
      int kk = st >> 2;
      int r4 = kchunk*4;
      float ev[2][4];
      #pragma unroll
      for (int rg=0;rg<2;rg++)
        #pragma unroll
        for (int r=0;r<4;r++)
          ev[rg][r] = e_s[(wid*32 + rg*16 + r4 + r)*KEXP + kk];
      #pragma unroll
      for (int rg=0;rg<2;rg++)
        #pragma unroll
        for (int cg=0;cg<8;cg++){
          #pragma unroll
          for (int r=0;r<4;r++)
            acc[rg][cg][r] += ev[rg][r]*ck[rg][cg][r];
          ck[rg][cg] = (f32x4){0.f,0.f,0.f,0.f};
        }
    }
    if (st+1 < NSTAGE){
      bf16_t* nbuf = b_s + ((st+1)&1)*STG_ELEMS;
      #pragma unroll
      for (int i=0;i<4;i++)
        *reinterpret_cast<int4*>(&nbuf[(i*256+tid)*8]) = breg[i];
    }
    __syncthreads();
  }

  // ---- epilogue: + residual
  int r4 = kchunk*4;
  #pragma unroll
  for (int rg=0;rg<2;rg++){
    #pragma unroll
    for (int cg=0; cg<8; cg++){
      int ocol = cg*16 + r16;
      #pragma unroll
      for (int r=0; r<4; r++){
        int node = base + wid*32 + rg*16 + r4 + r;
        if (node < Nn)
          out[(size_t)node*F + ocol] = acc[rg][cg][r] + x[(size_t)node*F + ocol];
      }
    }
  }
}

extern "C" void kernel_launch(void* const* d_in, const int* in_sizes, int n_in,
                              void* d_out, int out_size, void* d_ws, size_t ws_size,
                              hipStream_t stream){
  const float* x  = (const float*)d_in[0];
  const int*  adj = (const int*)d_in[1];
  const float* e  = (const float*)d_in[2];
  const float* W  = (const float*)d_in[3];
  float* out = (float*)d_out;
  int Nn = in_sizes[0] / F;     // 50000
  int E  = in_sizes[1] / 2;     // 1600000
  const int* rowp = adj;
  const int* colp = adj + E;

  char* w = (char*)d_ws;
  auto alloc = [&](size_t b){ char* p = w; w += (b + 255) & ~(size_t)255; return p; };
  int* deg     = (int*)alloc((size_t)Nn*4);
  int* offs    = (int*)alloc(((size_t)Nn+1)*4);
  int* cursor  = (int*)alloc((size_t)NB*4);
  int* bstart  = (int*)alloc((size_t)(NB+1)*4);
  int* bucket  = (int*)alloc((size_t)E*4);
  char* uni    = alloc((size_t)Nn*F*2 > (size_t)NB*CAP*4 ? (size_t)Nn*F*2
                                                          : (size_t)NB*CAP*4);
  int* region  = (int*)uni;      // dead after k_binB
  bf16_t* xs   = (bf16_t*)uni;   // live from k_prep_xs
  bf16_t* hi   = (bf16_t*)alloc((size_t)Nn*F*2);
  bf16_t* Wt   = (bf16_t*)alloc((size_t)2048*F*2);

  int nchunks = (E + CH - 1) / CH;
  k_initcur<<<1, 256, 0, stream>>>(cursor);
  k_binA<<<nchunks, 256, 0, stream>>>(rowp, colp, cursor, region, E);
  k_bstart<<<1, 256, 0, stream>>>(cursor, bstart, offs, Nn);
  k_binB<<<NB, 256, 0, stream>>>(region, cursor, bstart, deg, offs, bucket, Nn);
  k_prep_xs<<<(Nn*F/8+255)/256, 256, 0, stream>>>(x, deg, xs, Nn*F/8);
  k_prep_w<<<(32768+255)/256, 256, 0, stream>>>(W, Wt);
  k_agg<<<(Nn+3)/4, 256, 0, stream>>>(xs, offs, bucket, hi, Nn);
  k_gemm<<<(Nn+BM-1)/BM, 256, 0, stream>>>(hi, x, e, Wt, out, Nn);
}